// Round 1
// baseline (512.139 us; speedup 1.0000x reference)
//
#include <hip/hip_runtime.h>

// Problem constants (from reference)
#define BB      4096
#define EE      128
#define MM      8
#define NSTEPS  3
#define HH      256
#define CC      16

#define TS      32                    // samples per block
#define NBMAX   (BB/TS + MM)          // 136: worst-case padded blocks per step
#define XROW    (EE + 4)              // 132: LDS row stride for x/bias (bank = (4s+e)%32)
#define HROW    (2*EE + 4)            // 260: LDS row stride for h   (bank = (4s+f)%32)

// ---------------------------------------------------------------------------
// prep: histogram module_ids per step, build padded bucket layout, scatter perm
// ---------------------------------------------------------------------------
__global__ __launch_bounds__(256) void prep_kernel(
    const int* __restrict__ module_ids,   // (B, NSTEPS)
    int* __restrict__ blockMod,           // (NSTEPS, NBMAX)   module per block, -1 = unused
    int* __restrict__ perm)               // (NSTEPS, NBMAX*TS) sample ids, -1 = pad
{
    __shared__ int counts[NSTEPS][MM];
    __shared__ int base  [NSTEPS][MM];
    __shared__ int cursor[NSTEPS][MM];
    const int tid = threadIdx.x;
    if (tid < NSTEPS*MM) { (&counts[0][0])[tid] = 0; (&cursor[0][0])[tid] = 0; }
    __syncthreads();

    for (int i = tid; i < BB*NSTEPS; i += 256) {
        const int s = i / NSTEPS, t = i % NSTEPS;
        atomicAdd(&counts[t][module_ids[s*NSTEPS + t]], 1);
    }
    for (int i = tid; i < NSTEPS*NBMAX*TS; i += 256) perm[i] = -1;
    __syncthreads();

    if (tid < NSTEPS) {            // tiny serial plan per step
        const int t = tid;
        int blk = 0;
        for (int m = 0; m < MM; m++) {
            base[t][m] = blk * TS;
            const int nb = (counts[t][m] + TS - 1) / TS;
            for (int b = 0; b < nb; b++) blockMod[t*NBMAX + blk + b] = m;
            blk += nb;
        }
        for (; blk < NBMAX; blk++) blockMod[t*NBMAX + blk] = -1;
    }
    __syncthreads();

    for (int i = tid; i < BB*NSTEPS; i += 256) {
        const int s = i / NSTEPS, t = i % NSTEPS;
        const int m = module_ids[s*NSTEPS + t];
        const int pos = base[t][m] + atomicAdd(&cursor[t][m], 1);
        perm[t*NBMAX*TS + pos] = s;
    }
}

// ---------------------------------------------------------------------------
// one recurrent step for a 32-sample, module-uniform block
// ---------------------------------------------------------------------------
__global__ __launch_bounds__(256) void step_kernel(
    const int t,
    const int*   __restrict__ entity_ids,  // (B, NSTEPS+1)
    const float* __restrict__ embedding,   // (N_ENT, E)
    const float* __restrict__ W_in,  const float* __restrict__ b_in,
    const float* __restrict__ W_bias, const float* __restrict__ b_bias,
    const float* __restrict__ W_f,   const float* __restrict__ b_f,
    const int*   __restrict__ blockMod,
    const int*   __restrict__ perm,
    float* __restrict__ xbuf)              // (B, E) state, updated in place
{
    const int bid = blockIdx.x;
    const int m = blockMod[t*NBMAX + bid];
    if (m < 0) return;                      // padded/unused block (uniform)
    const int tid = threadIdx.x;

    // xs+bs (2*32*132 floats) reused as hs (32*260 floats) after sync
    __shared__ __align__(16) float smem[2*TS*XROW];
    __shared__ int sid[TS];
    float (*xs)[XROW] = (float (*)[XROW])smem;
    float (*bs)[XROW] = (float (*)[XROW])(smem + TS*XROW);
    float (*hs)[HROW] = (float (*)[HROW])smem;

    if (tid < TS) sid[tid] = perm[(t*NBMAX + bid)*TS + tid];
    __syncthreads();

    // gather x (from embedding at t==0, else xbuf) and bias rows
    for (int j = tid; j < TS*(EE/4); j += 256) {
        const int r = j >> 5, q = j & 31;
        const int s = sid[r];
        float4 xv = make_float4(0.f,0.f,0.f,0.f);
        float4 bv = xv;
        if (s >= 0) {
            if (t == 0) {
                const int e0 = entity_ids[s*(NSTEPS+1)];
                xv = *(const float4*)(embedding + (size_t)e0*EE + q*4);
            } else {
                xv = *(const float4*)(xbuf + (size_t)s*EE + q*4);
            }
            const int e1 = entity_ids[s*(NSTEPS+1) + t + 1];
            bv = *(const float4*)(embedding + (size_t)e1*EE + q*4);
        }
        *(float4*)(&xs[r][q*4]) = xv;
        *(float4*)(&bs[r][q*4]) = bv;
    }
    __syncthreads();

    const int og = tid & 31, sg = tid >> 5;
    const int o0 = og*4, s0 = sg*4;

    // h_in = relu(x @ W_in[m] + b_in[m]); h_bi = relu(bias @ W_bias[m] + b_bias[m])
    float acc1[4][4] = {{0.f}};
    float acc2[4][4] = {{0.f}};
    {
        const float* __restrict__ Wi = W_in  + (size_t)m*EE*EE + o0;
        const float* __restrict__ Wb = W_bias + (size_t)m*EE*EE + o0;
        #pragma unroll 4
        for (int e = 0; e < EE; e++) {
            const float4 w1 = *(const float4*)(Wi + (size_t)e*EE);
            const float4 w2 = *(const float4*)(Wb + (size_t)e*EE);
            #pragma unroll
            for (int si = 0; si < 4; si++) {
                const float xv = xs[s0+si][e];
                const float bv = bs[s0+si][e];
                acc1[si][0] = fmaf(xv, w1.x, acc1[si][0]);
                acc1[si][1] = fmaf(xv, w1.y, acc1[si][1]);
                acc1[si][2] = fmaf(xv, w1.z, acc1[si][2]);
                acc1[si][3] = fmaf(xv, w1.w, acc1[si][3]);
                acc2[si][0] = fmaf(bv, w2.x, acc2[si][0]);
                acc2[si][1] = fmaf(bv, w2.y, acc2[si][1]);
                acc2[si][2] = fmaf(bv, w2.z, acc2[si][2]);
                acc2[si][3] = fmaf(bv, w2.w, acc2[si][3]);
            }
        }
    }
    __syncthreads();   // all xs/bs reads done; hs aliases that memory
    {
        const float4 bi = *(const float4*)(b_in  + m*EE + o0);
        const float4 bb = *(const float4*)(b_bias + m*EE + o0);
        #pragma unroll
        for (int si = 0; si < 4; si++) {
            float4 h1, h2;
            h1.x = fmaxf(acc1[si][0] + bi.x, 0.f);
            h1.y = fmaxf(acc1[si][1] + bi.y, 0.f);
            h1.z = fmaxf(acc1[si][2] + bi.z, 0.f);
            h1.w = fmaxf(acc1[si][3] + bi.w, 0.f);
            h2.x = fmaxf(acc2[si][0] + bb.x, 0.f);
            h2.y = fmaxf(acc2[si][1] + bb.y, 0.f);
            h2.z = fmaxf(acc2[si][2] + bb.z, 0.f);
            h2.w = fmaxf(acc2[si][3] + bb.w, 0.f);
            *(float4*)(&hs[s0+si][o0])      = h1;
            *(float4*)(&hs[s0+si][EE + o0]) = h2;
        }
    }
    __syncthreads();

    // x_new = tanh(h @ W_f[m] + b_f[m])
    float acc3[4][4] = {{0.f}};
    {
        const float* __restrict__ Wf = W_f + (size_t)m*2*EE*EE + o0;
        #pragma unroll 4
        for (int f = 0; f < 2*EE; f++) {
            const float4 w = *(const float4*)(Wf + (size_t)f*EE);
            #pragma unroll
            for (int si = 0; si < 4; si++) {
                const float hv = hs[s0+si][f];
                acc3[si][0] = fmaf(hv, w.x, acc3[si][0]);
                acc3[si][1] = fmaf(hv, w.y, acc3[si][1]);
                acc3[si][2] = fmaf(hv, w.z, acc3[si][2]);
                acc3[si][3] = fmaf(hv, w.w, acc3[si][3]);
            }
        }
    }
    {
        const float4 bf = *(const float4*)(b_f + m*EE + o0);
        #pragma unroll
        for (int si = 0; si < 4; si++) {
            const int s = sid[s0+si];
            if (s >= 0) {
                float4 xn;
                xn.x = tanhf(acc3[si][0] + bf.x);
                xn.y = tanhf(acc3[si][1] + bf.y);
                xn.z = tanhf(acc3[si][2] + bf.z);
                xn.w = tanhf(acc3[si][3] + bf.w);
                *(float4*)(xbuf + (size_t)s*EE + o0) = xn;
            }
        }
    }
}

// ---------------------------------------------------------------------------
// head: out = relu(x @ W1 + b1) @ W2 + b2
// ---------------------------------------------------------------------------
__global__ __launch_bounds__(256) void final_kernel(
    const float* __restrict__ xbuf,
    const float* __restrict__ W1, const float* __restrict__ b1,
    const float* __restrict__ W2, const float* __restrict__ b2,
    float* __restrict__ out)
{
    const int tid = threadIdx.x, bid = blockIdx.x;
    const int sbase = bid * TS;
    __shared__ __align__(16) float smem[TS*(HH+4)];   // hs (8320 floats); xs aliases front
    float (*xs)[XROW]  = (float (*)[XROW])smem;
    float (*hs)[HH+4]  = (float (*)[HH+4])smem;

    for (int j = tid; j < TS*(EE/4); j += 256) {
        const int r = j >> 5, q = j & 31;
        *(float4*)(&xs[r][q*4]) = *(const float4*)(xbuf + (size_t)(sbase + r)*EE + q*4);
    }
    __syncthreads();

    const int og = tid & 31, sg = tid >> 5;
    const int o0 = og*8, s0 = sg*4;
    float acc[4][8] = {{0.f}};
    #pragma unroll 2
    for (int e = 0; e < EE; e++) {
        const float4 wa = *(const float4*)(W1 + (size_t)e*HH + o0);
        const float4 wb = *(const float4*)(W1 + (size_t)e*HH + o0 + 4);
        #pragma unroll
        for (int si = 0; si < 4; si++) {
            const float xv = xs[s0+si][e];
            acc[si][0] = fmaf(xv, wa.x, acc[si][0]);
            acc[si][1] = fmaf(xv, wa.y, acc[si][1]);
            acc[si][2] = fmaf(xv, wa.z, acc[si][2]);
            acc[si][3] = fmaf(xv, wa.w, acc[si][3]);
            acc[si][4] = fmaf(xv, wb.x, acc[si][4]);
            acc[si][5] = fmaf(xv, wb.y, acc[si][5]);
            acc[si][6] = fmaf(xv, wb.z, acc[si][6]);
            acc[si][7] = fmaf(xv, wb.w, acc[si][7]);
        }
    }
    __syncthreads();   // xs reads done; hs aliases
    {
        const float4 ba = *(const float4*)(b1 + o0);
        const float4 bb = *(const float4*)(b1 + o0 + 4);
        #pragma unroll
        for (int si = 0; si < 4; si++) {
            float4 h1, h2;
            h1.x = fmaxf(acc[si][0] + ba.x, 0.f);
            h1.y = fmaxf(acc[si][1] + ba.y, 0.f);
            h1.z = fmaxf(acc[si][2] + ba.z, 0.f);
            h1.w = fmaxf(acc[si][3] + ba.w, 0.f);
            h2.x = fmaxf(acc[si][4] + bb.x, 0.f);
            h2.y = fmaxf(acc[si][5] + bb.y, 0.f);
            h2.z = fmaxf(acc[si][6] + bb.z, 0.f);
            h2.w = fmaxf(acc[si][7] + bb.w, 0.f);
            *(float4*)(&hs[s0+si][o0])     = h1;
            *(float4*)(&hs[s0+si][o0 + 4]) = h2;
        }
    }
    __syncthreads();
    {
        const int s  = tid >> 3;         // 32 samples
        const int c0 = (tid & 7) * 2;    // 8 column pairs
        float a0 = 0.f, a1 = 0.f;
        #pragma unroll 4
        for (int f = 0; f < HH; f++) {
            const float hv = hs[s][f];
            a0 = fmaf(hv, W2[f*CC + c0],     a0);
            a1 = fmaf(hv, W2[f*CC + c0 + 1], a1);
        }
        out[(size_t)(sbase + s)*CC + c0]     = a0 + b2[c0];
        out[(size_t)(sbase + s)*CC + c0 + 1] = a1 + b2[c0 + 1];
    }
}

// ---------------------------------------------------------------------------
extern "C" void kernel_launch(void* const* d_in, const int* in_sizes, int n_in,
                              void* d_out, int out_size, void* d_ws, size_t ws_size,
                              hipStream_t stream) {
    const int*   entity_ids = (const int*)  d_in[0];
    const int*   module_ids = (const int*)  d_in[1];
    const float* embedding  = (const float*)d_in[2];
    const float* W_in   = (const float*)d_in[3];
    const float* b_in   = (const float*)d_in[4];
    const float* W_bias = (const float*)d_in[5];
    const float* b_bias = (const float*)d_in[6];
    const float* W_f    = (const float*)d_in[7];
    const float* b_f    = (const float*)d_in[8];
    const float* W1     = (const float*)d_in[9];
    const float* b1     = (const float*)d_in[10];
    const float* W2     = (const float*)d_in[11];
    const float* b2     = (const float*)d_in[12];
    float* out = (float*)d_out;

    // workspace layout: blockMod (512 ints) | perm (3*136*32 ints) | xbuf (B*E floats)
    int* blockMod = (int*)d_ws;
    int* perm     = blockMod + 512;
    float* xbuf   = (float*)(blockMod + 512 + NSTEPS*NBMAX*TS);  // byte off 54272, 16B-aligned

    prep_kernel<<<1, 256, 0, stream>>>(module_ids, blockMod, perm);
    for (int t = 0; t < NSTEPS; t++) {
        step_kernel<<<NBMAX, 256, 0, stream>>>(t, entity_ids, embedding,
                                               W_in, b_in, W_bias, b_bias, W_f, b_f,
                                               blockMod, perm, xbuf);
    }
    final_kernel<<<BB/TS, 256, 0, stream>>>(xbuf, W1, b1, W2, b2, out);
}